// Round 4
// baseline (92.981 us; speedup 1.0000x reference)
//
#include <hip/hip_runtime.h>
#include <hip/hip_cooperative_groups.h>
#include <math.h>
#include <float.h>

namespace cg = cooperative_groups;

#define BB 16
#define NN 2382
#define EPSF 1e-5f
#define NTILE 64
#define CHM 596            // ceil(NN/4), even
#define NV4 9528           // BB*NN/4
#define NXT 38             // n-tiles
#define NBLK 608           // NXT*BB
#define L2E 1.4426950408889634f

// ws float layout: y-stat partial arrays (written phase C, read phase D)
#define WS_YS 0
#define WS_YQ 1024

__global__ __launch_bounds__(256, 3) void fused(
    const float* __restrict__ z,  const float* __restrict__ w1,
    const float* __restrict__ g1, const float* __restrict__ be1,
    const float* __restrict__ wq, const float* __restrict__ bqp,
    const float* __restrict__ wk, const float* __restrict__ bkp,
    const float* __restrict__ wv, const float* __restrict__ bv,
    const float* __restrict__ gammap,
    const float* __restrict__ w2, const float* __restrict__ b2p,
    const float* __restrict__ g2, const float* __restrict__ be2,
    float* __restrict__ ws, float* __restrict__ out)
{
    __shared__ float2 sKP[NN];     // {K[m], P[m]} per batch
    __shared__ float2 sPart[256];  // per-(wave,lane) {den,num}
    __shared__ float  sred[8];
    const int tid  = threadIdx.x;
    const int wave = tid >> 6, lane = tid & 63;
    const int b    = blockIdx.y;                 // batch
    const int bid  = b * NXT + blockIdx.x;       // linear block id

    // ---------- Phase A: z stats (redundant per block; z is L2-resident) ----
    const float4* __restrict__ z4 = (const float4*)z;
    float s = 0.f, s2 = 0.f;
    #pragma unroll 4
    for (int i = tid; i < NV4; i += 256) {
        float4 v = z4[i];
        s += v.x + v.y + v.z + v.w;
        s2 = fmaf(v.x,v.x, fmaf(v.y,v.y, fmaf(v.z,v.z, fmaf(v.w,v.w, s2))));
    }
    #pragma unroll
    for (int off = 32; off; off >>= 1) {
        s  += __shfl_xor(s, off);
        s2 += __shfl_xor(s2, off);
    }
    if (lane == 0) { sred[wave] = s; sred[4+wave] = s2; }
    __syncthreads();
    const float invn = 1.f / (float)(BB*NN);
    const float mz = (sred[0]+sred[1]+sred[2]+sred[3]) * invn;
    const float vz = (sred[4]+sred[5]+sred[6]+sred[7]) * invn - mz*mz;
    __syncthreads();   // sred reused below (kmax/kmin)

    // ---------- Phase B: derived params (redundant per block) ---------------
    float n1=0.f, nq=0.f, nk=0.f, n2=0.f;
    #pragma unroll
    for (int h=0; h<8; ++h) {
        n1 = fmaf(w1[h], w1[h], n1);
        nq = fmaf(wq[h], wq[h], nq);
        nk = fmaf(wk[h], wk[h], nk);
        n2 = fmaf(w2[h], w2[h], n2);
    }
    n1 = sqrtf(n1); nq = sqrtf(nq); nk = sqrtf(nk); n2 = sqrtf(n2);

    // wave-parallel power iteration on M = wv^T wv (lane=(i,j), all waves)
    const int pi = lane >> 3, pj = lane & 7;
    float Mij = 0.f;
    #pragma unroll
    for (int o = 0; o < 8; ++o) Mij = fmaf(wv[o*8+pi], wv[o*8+pj], Mij);
    float u = 1.f, nr = 1.f;
    for (int it = 0; it < 48; ++it) {
        float a = Mij * u;
        a += __shfl_xor(a, 1); a += __shfl_xor(a, 2); a += __shfl_xor(a, 4);
        float bb = a * a;
        bb += __shfl_xor(bb, 8); bb += __shfl_xor(bb, 16); bb += __shfl_xor(bb, 32);
        nr = sqrtf(bb);
        const float tj = __shfl(a, pj << 3);
        u = tj / nr;
    }
    const float invsig = rsqrtf(nr);   // 1/sigma_max(wv)

    float a1[8], c1[8], wqn[8], wkn[8], w2n[8], wvP[8];
    #pragma unroll
    for (int h=0; h<8; ++h) {
        const float w1n = w1[h] / n1;
        const float rs = rsqrtf(fmaf(w1n*w1n, vz, EPSF));
        a1[h]  = w1n * rs * g1[h];           // x_h = relu(a1*z + c1)
        c1[h]  = be1[h] - mz * a1[h];        // b1 cancels in train-mode BN
        wqn[h] = wq[h] / nq;
        wkn[h] = wk[h] / nk;
        w2n[h] = w2[h] / n2;
    }
    float bvP = 0.f;
    #pragma unroll
    for (int h=0; h<8; ++h) bvP = fmaf(w2n[h], bv[h], bvP);
    #pragma unroll
    for (int c=0; c<8; ++c) {
        float a = 0.f;
        #pragma unroll
        for (int h=0; h<8; ++h) a = fmaf(w2n[h], wv[h*8+c], a);
        wvP[c] = a * invsig;
    }
    const float bq = bqp[0], bk = bkp[0], b2 = b2p[0], gamma = gammap[0];

    // ---------- Phase C: stage K,P; rank-1 attention ------------------------
    const float* __restrict__ zb = z + b*NN;
    float lmax = -FLT_MAX, lmin = FLT_MAX;
    for (int m = tid; m < NN; m += 256) {
        const float zv = zb[m];
        float xh[8];
        #pragma unroll
        for (int h=0;h<8;++h) xh[h] = fmaxf(fmaf(a1[h], zv, c1[h]), 0.f);
        float kk = bk, pp = bvP;
        #pragma unroll
        for (int h=0;h<8;++h) { kk = fmaf(wkn[h], xh[h], kk); pp = fmaf(wvP[h], xh[h], pp); }
        sKP[m] = make_float2(kk, pp);
        lmax = fmaxf(lmax, kk); lmin = fminf(lmin, kk);
    }
    #pragma unroll
    for (int off=32; off; off>>=1) {
        lmax = fmaxf(lmax, __shfl_xor(lmax, off));
        lmin = fminf(lmin, __shfl_xor(lmin, off));
    }
    if (lane == 0) { sred[wave] = lmax; sred[4+wave] = lmin; }
    __syncthreads();
    const float kmax = fmaxf(fmaxf(sred[0],sred[1]), fmaxf(sred[2],sred[3]));
    const float kmin = fminf(fminf(sred[4],sred[5]), fminf(sred[6],sred[7]));

    const int n = blockIdx.x*NTILE + lane;
    float q = 0.f, r = 0.f;
    if (n < NN) {
        const float zv = zb[n];
        float xh[8];
        #pragma unroll
        for (int h=0;h<8;++h) xh[h] = fmaxf(fmaf(a1[h], zv, c1[h]), 0.f);
        q = bq; r = b2;
        #pragma unroll
        for (int h=0;h<8;++h) { q = fmaf(wqn[h], xh[h], q); r = fmaf(w2n[h], xh[h], r); }
    }
    const float smax = (q >= 0.f) ? q*kmax : q*kmin;   // max_m q*K[m]
    const float q2 = q * L2E;
    const float s2e = smax * L2E;

    const int m0 = wave*CHM;
    const int m1 = (m0 + CHM < NN) ? m0 + CHM : NN;    // m0 even, count even
    float den0=0.f, den1=0.f, num0=0.f, num1=0.f;
    #pragma unroll 4
    for (int m = m0; m+2 <= m1; m += 2) {
        const float4 kp = *(const float4*)(&sKP[m]);   // {K,P,K,P}
        const float e0 = __builtin_amdgcn_exp2f(fmaf(q2, kp.x, -s2e));
        const float e1 = __builtin_amdgcn_exp2f(fmaf(q2, kp.z, -s2e));
        den0 += e0; num0 = fmaf(e0, kp.y, num0);
        den1 += e1; num1 = fmaf(e1, kp.w, num1);
    }
    sPart[tid] = make_float2(den0+den1, num0+num1);
    __syncthreads();

    float yv = 0.f;
    if (tid < NTILE && n < NN) {
        const float2 p0 = sPart[tid];
        const float2 p1 = sPart[64+tid];
        const float2 p2 = sPart[128+tid];
        const float2 p3 = sPart[192+tid];
        const float den = p0.x+p1.x+p2.x+p3.x;
        const float num = p0.y+p1.y+p2.y+p3.y;
        yv = r + gamma*num/den;        // pre-BN2 y, kept in registers
    }
    if (tid < 64) {                    // wave 0: block-partial y stats
        float sy = yv, sy2 = yv*yv;    // OOB lanes contribute 0
        #pragma unroll
        for (int off=32; off; off>>=1) {
            sy  += __shfl_xor(sy,  off);
            sy2 += __shfl_xor(sy2, off);
        }
        if (tid == 0) { ws[WS_YS+bid] = sy; ws[WS_YQ+bid] = sy2; }
    }

    cg::this_grid().sync();

    // ---------- Phase D: global y stats + BN2 + ReLU (wave 0 only) ----------
    if (wave == 0) {
        float ts = 0.f, tq = 0.f;
        for (int i = lane; i < NBLK; i += 64) {
            ts += ws[WS_YS+i];
            tq += ws[WS_YQ+i];
        }
        #pragma unroll
        for (int off=32; off; off>>=1) {
            ts += __shfl_xor(ts, off);
            tq += __shfl_xor(tq, off);
        }
        const float my = ts * invn;
        const float vy = tq * invn - my*my;
        const float sc = g2[0] * rsqrtf(vy + EPSF);
        const float sh = be2[0] - my * sc;
        if (n < NN) out[b*NN + n] = fmaxf(fmaf(yv, sc, sh), 0.f);
    }
}

extern "C" void kernel_launch(void* const* d_in, const int* in_sizes, int n_in,
                              void* d_out, int out_size, void* d_ws, size_t ws_size,
                              hipStream_t stream)
{
    const float* z    = (const float*)d_in[0];
    const float* w1   = (const float*)d_in[1];
    // d_in[2] = b1 (cancels in train-mode BN1)
    const float* g1   = (const float*)d_in[3];
    const float* be1  = (const float*)d_in[4];
    const float* wq   = (const float*)d_in[5];
    const float* bq   = (const float*)d_in[6];
    const float* wk   = (const float*)d_in[7];
    const float* bk   = (const float*)d_in[8];
    const float* wv   = (const float*)d_in[9];
    const float* bv   = (const float*)d_in[10];
    const float* gamma= (const float*)d_in[11];
    const float* w2   = (const float*)d_in[12];
    const float* b2   = (const float*)d_in[13];
    const float* g2   = (const float*)d_in[14];
    const float* be2  = (const float*)d_in[15];
    float* ws  = (float*)d_ws;
    float* out = (float*)d_out;

    void* args[] = { (void*)&z, (void*)&w1, (void*)&g1, (void*)&be1,
                     (void*)&wq, (void*)&bq, (void*)&wk, (void*)&bk,
                     (void*)&wv, (void*)&bv, (void*)&gamma,
                     (void*)&w2, (void*)&b2, (void*)&g2, (void*)&be2,
                     (void*)&ws, (void*)&out };
    hipLaunchCooperativeKernel((const void*)fused, dim3(NXT, BB), dim3(256),
                               args, 0, stream);
}

// Round 5
// 43.537 us; speedup vs baseline: 2.1357x; 2.1357x over previous
//
#include <hip/hip_runtime.h>
#include <math.h>
#include <float.h>

#define BB 16
#define NN 2382
#define EPSF 1e-5f
#define NTILE 64
#define CHM 596            // ceil(NN/4), even
#define NV4 9528           // BB*NN/4
#define NXT 38             // n-tiles
#define NBLK 608           // NXT*BB
#define L2E 1.4426950408889634f

// ws float layout
#define WS_Y   0           // 38112 floats: pre-BN2 y
#define WS_YS  38912       // 608 block partial sums
#define WS_YQ  39552       // 608 block partial sumsq

__global__ __launch_bounds__(256) void ka_attn(
    const float* __restrict__ z,  const float* __restrict__ w1,
    const float* __restrict__ g1, const float* __restrict__ be1,
    const float* __restrict__ wq, const float* __restrict__ bqp,
    const float* __restrict__ wk, const float* __restrict__ bkp,
    const float* __restrict__ wv, const float* __restrict__ bv,
    const float* __restrict__ gammap,
    const float* __restrict__ w2, const float* __restrict__ b2p,
    float* __restrict__ ws)
{
    __shared__ float2 sKP[NN];     // {K[m], P[m]} per batch
    __shared__ float2 sPart[256];  // per-(wave,lane) {den,num}
    __shared__ float  sred[8];
    const int tid  = threadIdx.x;
    const int wave = tid >> 6, lane = tid & 63;
    const int b    = blockIdx.y;                 // batch
    const int bid  = b * NXT + blockIdx.x;       // linear block id

    // ---------- Phase A: z stats (redundant per block; L2-resident) ---------
    const float4* __restrict__ z4 = (const float4*)z;
    float s = 0.f, s2 = 0.f;
    #pragma unroll 4
    for (int i = tid; i < NV4; i += 256) {
        float4 v = z4[i];
        s += v.x + v.y + v.z + v.w;
        s2 = fmaf(v.x,v.x, fmaf(v.y,v.y, fmaf(v.z,v.z, fmaf(v.w,v.w, s2))));
    }
    #pragma unroll
    for (int off = 32; off; off >>= 1) {
        s  += __shfl_xor(s, off);
        s2 += __shfl_xor(s2, off);
    }
    if (lane == 0) { sred[wave] = s; sred[4+wave] = s2; }
    __syncthreads();
    const float invn = 1.f / (float)(BB*NN);
    const float mz = (sred[0]+sred[1]+sred[2]+sred[3]) * invn;
    const float vz = (sred[4]+sred[5]+sred[6]+sred[7]) * invn - mz*mz;
    __syncthreads();   // sred reused below

    // ---------- Phase B: derived params (redundant per block) ---------------
    float n1=0.f, nq=0.f, nk=0.f, n2=0.f;
    #pragma unroll
    for (int h=0; h<8; ++h) {
        n1 = fmaf(w1[h], w1[h], n1);
        nq = fmaf(wq[h], wq[h], nq);
        nk = fmaf(wk[h], wk[h], nk);
        n2 = fmaf(w2[h], w2[h], n2);
    }
    n1 = sqrtf(n1); nq = sqrtf(nq); nk = sqrtf(nk); n2 = sqrtf(n2);

    // wave-parallel power iteration on M = wv^T wv (lane=(i,j))
    const int pi = lane >> 3, pj = lane & 7;
    float Mij = 0.f;
    #pragma unroll
    for (int o = 0; o < 8; ++o) Mij = fmaf(wv[o*8+pi], wv[o*8+pj], Mij);
    float u = 1.f, nr = 1.f;
    for (int it = 0; it < 32; ++it) {
        float a = Mij * u;
        a += __shfl_xor(a, 1); a += __shfl_xor(a, 2); a += __shfl_xor(a, 4);
        float bb = a * a;
        bb += __shfl_xor(bb, 8); bb += __shfl_xor(bb, 16); bb += __shfl_xor(bb, 32);
        nr = sqrtf(bb);
        const float tj = __shfl(a, pj << 3);
        u = tj / nr;
    }
    const float invsig = rsqrtf(nr);   // 1/sigma_max(wv)

    float a1[8], c1[8], wqn[8], wkn[8], w2n[8], wvP[8];
    #pragma unroll
    for (int h=0; h<8; ++h) {
        const float w1n = w1[h] / n1;
        const float rs = rsqrtf(fmaf(w1n*w1n, vz, EPSF));
        a1[h]  = w1n * rs * g1[h];           // x_h = relu(a1*z + c1)
        c1[h]  = be1[h] - mz * a1[h];        // b1 cancels in train-mode BN
        wqn[h] = wq[h] / nq;
        wkn[h] = wk[h] / nk;
        w2n[h] = w2[h] / n2;
    }
    float bvP = 0.f;
    #pragma unroll
    for (int h=0; h<8; ++h) bvP = fmaf(w2n[h], bv[h], bvP);
    #pragma unroll
    for (int c=0; c<8; ++c) {
        float a = 0.f;
        #pragma unroll
        for (int h=0; h<8; ++h) a = fmaf(w2n[h], wv[h*8+c], a);
        wvP[c] = a * invsig;
    }
    const float bq = bqp[0], bk = bkp[0], b2 = b2p[0], gamma = gammap[0];

    // ---------- Phase C: stage K,P; rank-1 attention ------------------------
    const float* __restrict__ zb = z + b*NN;
    float lmax = -FLT_MAX, lmin = FLT_MAX;
    for (int m = tid; m < NN; m += 256) {
        const float zv = zb[m];
        float xh[8];
        #pragma unroll
        for (int h=0;h<8;++h) xh[h] = fmaxf(fmaf(a1[h], zv, c1[h]), 0.f);
        float kk = bk, pp = bvP;
        #pragma unroll
        for (int h=0;h<8;++h) { kk = fmaf(wkn[h], xh[h], kk); pp = fmaf(wvP[h], xh[h], pp); }
        sKP[m] = make_float2(kk, pp);
        lmax = fmaxf(lmax, kk); lmin = fminf(lmin, kk);
    }
    #pragma unroll
    for (int off=32; off; off>>=1) {
        lmax = fmaxf(lmax, __shfl_xor(lmax, off));
        lmin = fminf(lmin, __shfl_xor(lmin, off));
    }
    if (lane == 0) { sred[wave] = lmax; sred[4+wave] = lmin; }
    __syncthreads();
    const float kmax = fmaxf(fmaxf(sred[0],sred[1]), fmaxf(sred[2],sred[3]));
    const float kmin = fminf(fminf(sred[4],sred[5]), fminf(sred[6],sred[7]));

    const int n = blockIdx.x*NTILE + lane;
    float q = 0.f, r = 0.f;
    if (n < NN) {
        const float zv = zb[n];
        float xh[8];
        #pragma unroll
        for (int h=0;h<8;++h) xh[h] = fmaxf(fmaf(a1[h], zv, c1[h]), 0.f);
        q = bq; r = b2;
        #pragma unroll
        for (int h=0;h<8;++h) { q = fmaf(wqn[h], xh[h], q); r = fmaf(w2n[h], xh[h], r); }
    }
    const float smax = (q >= 0.f) ? q*kmax : q*kmin;   // max_m q*K[m]
    const float q2 = q * L2E;
    const float s2e = smax * L2E;

    const int m0 = wave*CHM;
    const int m1 = (m0 + CHM < NN) ? m0 + CHM : NN;    // m0 even, count even
    float den0=0.f, den1=0.f, num0=0.f, num1=0.f;
    #pragma unroll 4
    for (int m = m0; m+2 <= m1; m += 2) {
        const float4 kp = *(const float4*)(&sKP[m]);   // {K,P,K,P}
        const float e0 = __builtin_amdgcn_exp2f(fmaf(q2, kp.x, -s2e));
        const float e1 = __builtin_amdgcn_exp2f(fmaf(q2, kp.z, -s2e));
        den0 += e0; num0 = fmaf(e0, kp.y, num0);
        den1 += e1; num1 = fmaf(e1, kp.w, num1);
    }
    sPart[tid] = make_float2(den0+den1, num0+num1);
    __syncthreads();

    float yv = 0.f;
    if (tid < NTILE && n < NN) {
        const float2 p0 = sPart[tid];
        const float2 p1 = sPart[64+tid];
        const float2 p2 = sPart[128+tid];
        const float2 p3 = sPart[192+tid];
        const float den = p0.x+p1.x+p2.x+p3.x;
        const float num = p0.y+p1.y+p2.y+p3.y;
        yv = r + gamma*num/den;            // pre-BN2 y
        ws[WS_Y + b*NN + n] = yv;
    }
    if (tid < 64) {                        // wave 0: block-partial y stats
        float sy = yv, sy2 = yv*yv;        // OOB lanes contribute 0
        #pragma unroll
        for (int off=32; off; off>>=1) {
            sy  += __shfl_xor(sy,  off);
            sy2 += __shfl_xor(sy2, off);
        }
        if (tid == 0) { ws[WS_YS+bid] = sy; ws[WS_YQ+bid] = sy2; }
    }
}

// 38 blocks: each redundantly reduces the 608 partial pairs (deterministic
// fixed-order), then applies BN2+ReLU to its float4 slice of y -> out.
__global__ __launch_bounds__(256) void kb_out(
    const float* __restrict__ ws, const float* __restrict__ g2,
    const float* __restrict__ be2, float* __restrict__ out)
{
    __shared__ float sred[8];
    const int tid = threadIdx.x;
    const int wave = tid >> 6, lane = tid & 63;
    float ts = 0.f, tq = 0.f;
    for (int i = tid; i < NBLK; i += 256) {
        ts += ws[WS_YS+i];
        tq += ws[WS_YQ+i];
    }
    #pragma unroll
    for (int off=32; off; off>>=1) {
        ts += __shfl_xor(ts, off);
        tq += __shfl_xor(tq, off);
    }
    if (lane == 0) { sred[wave] = ts; sred[4+wave] = tq; }
    __syncthreads();
    const float invn = 1.f/(float)(BB*NN);
    const float my = (sred[0]+sred[1]+sred[2]+sred[3]) * invn;
    const float vy = (sred[4]+sred[5]+sred[6]+sred[7]) * invn - my*my;
    const float sc = g2[0] * rsqrtf(vy + EPSF);
    const float sh = be2[0] - my * sc;

    const int i = blockIdx.x*256 + tid;
    if (i >= NV4) return;
    const float4 v = ((const float4*)(ws + WS_Y))[i];
    float4 o;
    o.x = fmaxf(fmaf(v.x, sc, sh), 0.f);
    o.y = fmaxf(fmaf(v.y, sc, sh), 0.f);
    o.z = fmaxf(fmaf(v.z, sc, sh), 0.f);
    o.w = fmaxf(fmaf(v.w, sc, sh), 0.f);
    ((float4*)out)[i] = o;
}

extern "C" void kernel_launch(void* const* d_in, const int* in_sizes, int n_in,
                              void* d_out, int out_size, void* d_ws, size_t ws_size,
                              hipStream_t stream)
{
    const float* z    = (const float*)d_in[0];
    const float* w1   = (const float*)d_in[1];
    // d_in[2] = b1 (cancels in train-mode BN1)
    const float* g1   = (const float*)d_in[3];
    const float* be1  = (const float*)d_in[4];
    const float* wq   = (const float*)d_in[5];
    const float* bq   = (const float*)d_in[6];
    const float* wk   = (const float*)d_in[7];
    const float* bk   = (const float*)d_in[8];
    const float* wv   = (const float*)d_in[9];
    const float* bv   = (const float*)d_in[10];
    const float* gamma= (const float*)d_in[11];
    const float* w2   = (const float*)d_in[12];
    const float* b2   = (const float*)d_in[13];
    const float* g2   = (const float*)d_in[14];
    const float* be2  = (const float*)d_in[15];
    float* ws  = (float*)d_ws;
    float* out = (float*)d_out;

    ka_attn<<<dim3(NXT, BB), 256, 0, stream>>>(
        z, w1, g1, be1, wq, bq, wk, bk, wv, bv, gamma, w2, b2, ws);

    kb_out<<<(NV4+255)/256, 256, 0, stream>>>(ws, g2, be2, out);
}

// Round 6
// 36.022 us; speedup vs baseline: 2.5812x; 1.2086x over previous
//
#include <hip/hip_runtime.h>
#include <math.h>
#include <float.h>

#define BB 16
#define NN 2382
#define EPSF 1e-5f
#define NV4 9528            // BB*NN/4
#define L2E 1.4426950408889634f
#define TT 128              // G-table nodes per batch
#define NZB 38              // z-stat partial blocks
#define NXB 10              // kb n-blocks per batch
#define NBB 160             // kb total blocks
#define MSUB 149            // m's per sub-thread in ka node eval (16*149>=NN)

// ws float layout
#define WS_ZS   0            // 38 z partial sums
#define WS_ZQ   64           // 38 z partial sumsq
#define WS_TAB  128          // 16*128 G table
#define WS_META 2176         // 16*2 {qmin, qinv}
#define WS_PAR  2240         // a1[8] c1[8] wqn[8] w2n[8]
#define WS_Y    4096         // 38112 pre-BN2 y
#define WS_YS   43008        // 160 y partial sums
#define WS_YQ   43264        // 160 y partial sumsq

__global__ __launch_bounds__(256) void k0_zstats(
    const float* __restrict__ z, float* __restrict__ ws)
{
    __shared__ float sred[8];
    const int tid = threadIdx.x;
    const int wave = tid >> 6, lane = tid & 63;
    const int i = blockIdx.x*256 + tid;
    float s = 0.f, s2 = 0.f;
    if (i < NV4) {
        const float4 v = ((const float4*)z)[i];
        s  = v.x + v.y + v.z + v.w;
        s2 = fmaf(v.x,v.x, fmaf(v.y,v.y, fmaf(v.z,v.z, v.w*v.w)));
    }
    #pragma unroll
    for (int off=32; off; off>>=1){ s += __shfl_xor(s,off); s2 += __shfl_xor(s2,off); }
    if (lane==0){ sred[wave]=s; sred[4+wave]=s2; }
    __syncthreads();
    if (tid==0) {
        ws[WS_ZS+blockIdx.x] = sred[0]+sred[1]+sred[2]+sred[3];
        ws[WS_ZQ+blockIdx.x] = sred[4]+sred[5]+sred[6]+sred[7];
    }
}

// grid (4 chunks, 16 batches) x 512 threads.
// Per block: params (redundant), stage K,P (full batch), q/k ranges,
// evaluate 32 G-table nodes (16 threads per node over m-subranges).
__global__ __launch_bounds__(512) void ka_table(
    const float* __restrict__ z,  const float* __restrict__ w1,
    const float* __restrict__ g1, const float* __restrict__ be1,
    const float* __restrict__ wq, const float* __restrict__ bqp,
    const float* __restrict__ wk, const float* __restrict__ bkp,
    const float* __restrict__ wv, const float* __restrict__ bv,
    const float* __restrict__ w2, float* __restrict__ ws)
{
    __shared__ float2 sKP[NN];       // {K[m], P[m]}
    __shared__ float  sPD[512], sPN[512];
    __shared__ float  sred[32];
    const int tid  = threadIdx.x;
    const int wave = tid >> 6, lane = tid & 63;
    const int b = blockIdx.y, chunk = blockIdx.x;

    // z stats from k0 partials (uniform -> scalar loads)
    float zs = 0.f, zq = 0.f;
    for (int i=0; i<NZB; ++i) { zs += ws[WS_ZS+i]; zq += ws[WS_ZQ+i]; }
    const float invn = 1.f/(float)(BB*NN);
    const float mz = zs*invn;
    const float vz = zq*invn - mz*mz;

    // wave-parallel power iteration on M = wv^T wv (lane=(i,j); redundant/wave)
    const int pi = lane >> 3, pj = lane & 7;
    float Mij = 0.f;
    #pragma unroll
    for (int o=0; o<8; ++o) Mij = fmaf(wv[o*8+pi], wv[o*8+pj], Mij);
    float u = 1.f, nr = 1.f;
    for (int it=0; it<32; ++it) {
        float a = Mij*u;
        a += __shfl_xor(a,1); a += __shfl_xor(a,2); a += __shfl_xor(a,4);
        float bb = a*a;
        bb += __shfl_xor(bb,8); bb += __shfl_xor(bb,16); bb += __shfl_xor(bb,32);
        nr = sqrtf(bb);
        u = __shfl(a, pj<<3) / nr;
    }
    const float invsig = rsqrtf(nr);   // 1/sigma_max(wv)

    // derived params
    float n1=0.f, nq=0.f, nk=0.f, n2=0.f;
    #pragma unroll
    for (int h=0; h<8; ++h) {
        n1 = fmaf(w1[h], w1[h], n1);
        nq = fmaf(wq[h], wq[h], nq);
        nk = fmaf(wk[h], wk[h], nk);
        n2 = fmaf(w2[h], w2[h], n2);
    }
    n1 = sqrtf(n1); nq = sqrtf(nq); nk = sqrtf(nk); n2 = sqrtf(n2);

    float a1[8], c1[8], wqn[8], wkn[8], w2n[8], wvP[8];
    #pragma unroll
    for (int h=0; h<8; ++h) {
        const float w1n = w1[h]/n1;
        const float rs = rsqrtf(fmaf(w1n*w1n, vz, EPSF));
        a1[h]  = w1n * rs * g1[h];          // x_h = relu(a1*z + c1)
        c1[h]  = be1[h] - mz*a1[h];         // b1 cancels in train-mode BN
        wqn[h] = wq[h]/nq;
        wkn[h] = wk[h]/nk;
        w2n[h] = w2[h]/n2;
    }
    float bvP = 0.f;
    #pragma unroll
    for (int h=0; h<8; ++h) bvP = fmaf(w2n[h], bv[h], bvP);
    #pragma unroll
    for (int c=0; c<8; ++c) {
        float a = 0.f;
        #pragma unroll
        for (int h=0; h<8; ++h) a = fmaf(w2n[h], wv[h*8+c], a);
        wvP[c] = a * invsig;
    }
    const float bq = bqp[0], bk = bkp[0];

    // stage K,P; track k and q ranges
    const float* __restrict__ zb = z + b*NN;
    float lkmax=-FLT_MAX, lkmin=FLT_MAX, lqmax=-FLT_MAX, lqmin=FLT_MAX;
    for (int m=tid; m<NN; m+=512) {
        const float zv = zb[m];
        float xh[8];
        #pragma unroll
        for (int h=0;h<8;++h) xh[h] = fmaxf(fmaf(a1[h], zv, c1[h]), 0.f);
        float kk = bk, pp = bvP, qq = bq;
        #pragma unroll
        for (int h=0;h<8;++h) {
            kk = fmaf(wkn[h], xh[h], kk);
            pp = fmaf(wvP[h], xh[h], pp);
            qq = fmaf(wqn[h], xh[h], qq);
        }
        sKP[m] = make_float2(kk, pp);
        lkmax = fmaxf(lkmax, kk); lkmin = fminf(lkmin, kk);
        lqmax = fmaxf(lqmax, qq); lqmin = fminf(lqmin, qq);
    }
    #pragma unroll
    for (int off=32; off; off>>=1) {
        lkmax = fmaxf(lkmax, __shfl_xor(lkmax, off));
        lkmin = fminf(lkmin, __shfl_xor(lkmin, off));
        lqmax = fmaxf(lqmax, __shfl_xor(lqmax, off));
        lqmin = fminf(lqmin, __shfl_xor(lqmin, off));
    }
    if (lane==0) {
        sred[wave*4+0]=lkmax; sred[wave*4+1]=lkmin;
        sred[wave*4+2]=lqmax; sred[wave*4+3]=lqmin;
    }
    __syncthreads();
    float kmax=-FLT_MAX, kmin=FLT_MAX, qmax=-FLT_MAX, qmin=FLT_MAX;
    #pragma unroll
    for (int j=0;j<8;++j) {
        kmax = fmaxf(kmax, sred[j*4+0]); kmin = fminf(kmin, sred[j*4+1]);
        qmax = fmaxf(qmax, sred[j*4+2]); qmin = fminf(qmin, sred[j*4+3]);
    }

    // evaluate 32 nodes: node = tid>>4, 16 sub-threads per node over m ranges
    const int node = tid >> 4, sub = tid & 15;
    const int gn = chunk*32 + node;
    const float xq = fmaf((qmax-qmin), (float)gn*(1.f/(float)(TT-1)), qmin);
    const float st = fmaxf(xq*kmax, xq*kmin);      // max_m xq*K[m]
    const float x2 = xq*L2E, st2 = st*L2E;
    float den=0.f, num=0.f;
    const int m0 = sub*MSUB;
    const int m1 = (m0+MSUB < NN) ? m0+MSUB : NN;
    for (int m=m0; m<m1; ++m) {
        const float2 kp = sKP[m];
        const float e = __builtin_amdgcn_exp2f(fmaf(x2, kp.x, -st2));
        den += e; num = fmaf(e, kp.y, num);
    }
    sPD[tid]=den; sPN[tid]=num;
    __syncthreads();
    if (tid < 32) {
        float d=0.f, nm=0.f;
        #pragma unroll
        for (int j=0;j<16;++j){ d += sPD[tid*16+j]; nm += sPN[tid*16+j]; }
        ws[WS_TAB + b*TT + chunk*32 + tid] = nm/d;   // den >= 1 (shifted)
    }
    if (tid == 0) {
        ws[WS_META + b*2]     = qmin;
        ws[WS_META + b*2 + 1] = (qmax>qmin) ? (float)(TT-1)/(qmax-qmin) : 0.f;
    }
    if (b==0 && chunk==0 && tid==0) {
        #pragma unroll
        for (int h=0;h<8;++h) {
            ws[WS_PAR+h]    = a1[h];
            ws[WS_PAR+8+h]  = c1[h];
            ws[WS_PAR+16+h] = wqn[h];
            ws[WS_PAR+24+h] = w2n[h];
        }
    }
}

// grid (10, 16) x 256: per n -> q, lerp G, y; block partial y stats.
__global__ __launch_bounds__(256) void kb_attn(
    const float* __restrict__ z, const float* __restrict__ bqp,
    const float* __restrict__ b2p, const float* __restrict__ gammap,
    float* __restrict__ ws)
{
    __shared__ float sG[TT];
    __shared__ float sred[8];
    const int tid = threadIdx.x, wave = tid>>6, lane = tid&63;
    const int b = blockIdx.y;
    const int n = blockIdx.x*256 + tid;
    if (tid < TT) sG[tid] = ws[WS_TAB + b*TT + tid];
    float a1[8], c1[8], wqn[8], w2n[8];
    #pragma unroll
    for (int h=0;h<8;++h) {
        a1[h]  = ws[WS_PAR+h];
        c1[h]  = ws[WS_PAR+8+h];
        wqn[h] = ws[WS_PAR+16+h];
        w2n[h] = ws[WS_PAR+24+h];
    }
    const float qmin = ws[WS_META+b*2], qinv = ws[WS_META+b*2+1];
    const float bq = bqp[0], b2 = b2p[0], gamma = gammap[0];
    __syncthreads();

    float yv = 0.f;
    if (n < NN) {
        const float zv = z[b*NN+n];
        float xh[8];
        #pragma unroll
        for (int h=0;h<8;++h) xh[h] = fmaxf(fmaf(a1[h], zv, c1[h]), 0.f);
        float q = bq, r = b2;
        #pragma unroll
        for (int h=0;h<8;++h) { q = fmaf(wqn[h], xh[h], q); r = fmaf(w2n[h], xh[h], r); }
        float uu = (q - qmin)*qinv;
        uu = fminf(fmaxf(uu, 0.f), (float)(TT-1));
        int i = (int)uu; if (i > TT-2) i = TT-2;
        const float f = uu - (float)i;
        const float g0 = sG[i], g1v = sG[i+1];
        yv = r + gamma*fmaf(f, g1v-g0, g0);
        ws[WS_Y + b*NN + n] = yv;
    }
    float sy = yv, sy2 = yv*yv;      // OOB lanes contribute 0
    #pragma unroll
    for (int off=32; off; off>>=1) { sy += __shfl_xor(sy,off); sy2 += __shfl_xor(sy2,off); }
    if (lane==0) { sred[wave]=sy; sred[4+wave]=sy2; }
    __syncthreads();
    if (tid==0) {
        const int blk = b*NXB + blockIdx.x;
        ws[WS_YS+blk] = sred[0]+sred[1]+sred[2]+sred[3];
        ws[WS_YQ+blk] = sred[4]+sred[5]+sred[6]+sred[7];
    }
}

// 38 blocks: redundant fixed-order reduce of 160 partial pairs; BN2+ReLU.
__global__ __launch_bounds__(256) void kc_out(
    const float* __restrict__ ws, const float* __restrict__ g2,
    const float* __restrict__ be2, float* __restrict__ out)
{
    __shared__ float sred[8];
    const int tid = threadIdx.x, wave = tid>>6, lane = tid&63;
    float ts=0.f, tq=0.f;
    if (tid < NBB) { ts = ws[WS_YS+tid]; tq = ws[WS_YQ+tid]; }
    #pragma unroll
    for (int off=32; off; off>>=1) { ts += __shfl_xor(ts,off); tq += __shfl_xor(tq,off); }
    if (lane==0) { sred[wave]=ts; sred[4+wave]=tq; }
    __syncthreads();
    const float invn = 1.f/(float)(BB*NN);
    const float my = (sred[0]+sred[1]+sred[2]+sred[3]) * invn;
    const float vy = (sred[4]+sred[5]+sred[6]+sred[7]) * invn - my*my;
    const float sc = g2[0]*rsqrtf(vy+EPSF);
    const float sh = be2[0] - my*sc;

    const int i = blockIdx.x*256 + tid;
    if (i >= NV4) return;
    const float4 v = ((const float4*)(ws + WS_Y))[i];
    float4 o;
    o.x = fmaxf(fmaf(v.x, sc, sh), 0.f);
    o.y = fmaxf(fmaf(v.y, sc, sh), 0.f);
    o.z = fmaxf(fmaf(v.z, sc, sh), 0.f);
    o.w = fmaxf(fmaf(v.w, sc, sh), 0.f);
    ((float4*)out)[i] = o;
}

extern "C" void kernel_launch(void* const* d_in, const int* in_sizes, int n_in,
                              void* d_out, int out_size, void* d_ws, size_t ws_size,
                              hipStream_t stream)
{
    const float* z    = (const float*)d_in[0];
    const float* w1   = (const float*)d_in[1];
    // d_in[2] = b1 (cancels in train-mode BN1)
    const float* g1   = (const float*)d_in[3];
    const float* be1  = (const float*)d_in[4];
    const float* wq   = (const float*)d_in[5];
    const float* bq   = (const float*)d_in[6];
    const float* wk   = (const float*)d_in[7];
    const float* bk   = (const float*)d_in[8];
    const float* wv   = (const float*)d_in[9];
    const float* bv   = (const float*)d_in[10];
    const float* gamma= (const float*)d_in[11];
    const float* w2   = (const float*)d_in[12];
    const float* b2   = (const float*)d_in[13];
    const float* g2   = (const float*)d_in[14];
    const float* be2  = (const float*)d_in[15];
    float* ws  = (float*)d_ws;
    float* out = (float*)d_out;

    k0_zstats<<<NZB, 256, 0, stream>>>(z, ws);

    ka_table<<<dim3(4, BB), 512, 0, stream>>>(
        z, w1, g1, be1, wq, bq, wk, bk, wv, bv, w2, ws);

    kb_attn<<<dim3(NXB, BB), 256, 0, stream>>>(z, bq, b2, gamma, ws);

    kc_out<<<NZB, 256, 0, stream>>>(ws, g2, be2, out);
}